// Round 2
// baseline (435.067 us; speedup 1.0000x reference)
//
#include <hip/hip_runtime.h>
#include <stdint.h>

// Problem: B=4, T=4096, C=1024, H=16, HD=64, NBLOCKS=32, BSIZE=128
// out = (blockwise-MHA(x)) @ Wo^T + bo, all f32 in/out, bf16 compute inside.
#define Bb   4
#define Tt   4096
#define Cc   1024
#define Hh   16
#define HDd  64
#define NBn  32
#define BSs  128
#define MTOT (Bb*Tt)   // 16384 rows

typedef short s16;
typedef __attribute__((ext_vector_type(8))) short  short8;   // 8 bf16 (4 VGPRs) - MFMA A/B frag
typedef __attribute__((ext_vector_type(4))) float  f32x4;    // MFMA C/D frag
typedef __attribute__((ext_vector_type(4))) int    int4v;

__device__ __forceinline__ s16 f2bf(float f) {   // f32 -> bf16, RNE
  union { float f; uint32_t u; } c; c.f = f;
  return (s16)((c.u + 0x7fffu + ((c.u >> 16) & 1u)) >> 16);
}

typedef const __attribute__((address_space(1))) void* gas_p;
typedef __attribute__((address_space(3))) void*       las_p;
__device__ __forceinline__ void lds16(const void* g, void* l) {
  // async global->LDS, 16B per lane; LDS dest = wave-uniform base + lane*16
  __builtin_amdgcn_global_load_lds((gas_p)g, (las_p)l, 16, 0, 0);
}

// ---------------- f32 -> bf16 conversion kernels ----------------
__global__ __launch_bounds__(256) void cvt_x(const float* __restrict__ in, s16* __restrict__ out) {
  int i = blockIdx.x * 256 + threadIdx.x;          // 2,097,152 threads, 8 elems each
  const f32x4* p = (const f32x4*)(in + (size_t)i * 8);
  f32x4 a = p[0], b = p[1];
  short8 o;
  o[0]=f2bf(a[0]); o[1]=f2bf(a[1]); o[2]=f2bf(a[2]); o[3]=f2bf(a[3]);
  o[4]=f2bf(b[0]); o[5]=f2bf(b[1]); o[6]=f2bf(b[2]); o[7]=f2bf(b[3]);
  *(short8*)(out + (size_t)i * 8) = o;
}

__global__ __launch_bounds__(256) void cvt_w(const float* w0, const float* w1,
                                             const float* w2, const float* w3,
                                             s16* o0, s16* o1, s16* o2, s16* o3) {
  int i = blockIdx.x * 256 + threadIdx.x;          // 4 x 131072 slots of 8 elems
  int which = i >> 17;
  int j = i & 131071;
  const float* w = which == 0 ? w0 : which == 1 ? w1 : which == 2 ? w2 : w3;
  s16*         o = which == 0 ? o0 : which == 1 ? o1 : which == 2 ? o2 : o3;
  const f32x4* p = (const f32x4*)(w + (size_t)j * 8);
  f32x4 a = p[0], b = p[1];
  short8 v;
  v[0]=f2bf(a[0]); v[1]=f2bf(a[1]); v[2]=f2bf(a[2]); v[3]=f2bf(a[3]);
  v[4]=f2bf(b[0]); v[5]=f2bf(b[1]); v[6]=f2bf(b[2]); v[7]=f2bf(b[3]);
  *(short8*)(o + (size_t)j * 8) = v;
}

// ---------------- bt-GEMM: C[m,n] = sum_k A[m,k]*W[n,k] (+bias[n]) ----------------
// m97-class: 128x128 tile, BK=32, 4 waves, 4x4 16x16x32 frags/wave, global_load_lds w=16.
// LDS kg-slot swizzle: content (r,kg) lives at slot j = kg ^ ((r>>1)&3) (2 lanes/bank on frag reads),
// applied by pre-swizzling the GLOBAL source address (LDS dest of global_load_lds must stay linear).
template <bool OUT_BF16>
__global__ __launch_bounds__(256) void gemm_bt(const s16* __restrict__ A, const s16* __restrict__ Bm,
                                               const float* __restrict__ bias, void* __restrict__ Cout,
                                               int M, int N, int K) {
  __shared__ s16 As[128 * 32];   // 512 slots of 16B
  __shared__ s16 Bs[128 * 32];

  const int tid = threadIdx.x;
  const int w = tid >> 6;
  const int l = tid & 63;
  const int lr = l & 15, lk = l >> 4;
  const int wr = w >> 1, wc = w & 1;          // 64x64 quadrant per wave
  const int mBase = blockIdx.y * 128;
  const int nBase = blockIdx.x * 128;

  f32x4 acc[4][4];
#pragma unroll
  for (int i = 0; i < 4; ++i)
#pragma unroll
    for (int j = 0; j < 4; ++j) acc[i][j] = (f32x4){0.f, 0.f, 0.f, 0.f};

  for (int k0 = 0; k0 < K; k0 += 32) {
    // stage 128x32 A and B tiles (each: 512 slots, 2 per thread)
#pragma unroll
    for (int t = 0; t < 2; ++t) {
      int s = t * 256 + tid;
      int r = s >> 2, j = s & 3;
      int kg = j ^ ((r >> 1) & 3);
      const s16* ga = A  + (size_t)(mBase + r) * K + (k0 + kg * 8);
      const s16* gb = Bm + (size_t)(nBase + r) * K + (k0 + kg * 8);
      lds16(ga, &As[(t * 256 + w * 64) * 8]);
      lds16(gb, &Bs[(t * 256 + w * 64) * 8]);
    }
    __syncthreads();

    short8 af[4], bf[4];
#pragma unroll
    for (int mt = 0; mt < 4; ++mt) {
      int row = wr * 64 + mt * 16 + lr;
      af[mt] = *(const short8*)&As[(row * 4 + (lk ^ ((row >> 1) & 3))) * 8];
    }
#pragma unroll
    for (int nt = 0; nt < 4; ++nt) {
      int row = wc * 64 + nt * 16 + lr;
      bf[nt] = *(const short8*)&Bs[(row * 4 + (lk ^ ((row >> 1) & 3))) * 8];
    }
#pragma unroll
    for (int mt = 0; mt < 4; ++mt)
#pragma unroll
      for (int nt = 0; nt < 4; ++nt)
        acc[mt][nt] = __builtin_amdgcn_mfma_f32_16x16x32_bf16(af[mt], bf[nt], acc[mt][nt], 0, 0, 0);
    __syncthreads();
  }

  // epilogue: C/D layout col=lane&15, row=(lane>>4)*4+i
#pragma unroll
  for (int nt = 0; nt < 4; ++nt) {
    int col = nBase + wc * 64 + nt * 16 + lr;
    float bv = bias ? bias[col] : 0.0f;
#pragma unroll
    for (int mt = 0; mt < 4; ++mt) {
      int row0 = mBase + wr * 64 + mt * 16 + lk * 4;
#pragma unroll
      for (int i = 0; i < 4; ++i) {
        float v = acc[mt][nt][i] + bv;
        if (OUT_BF16) ((s16*)Cout)[(size_t)(row0 + i) * N + col] = f2bf(v);
        else          ((float*)Cout)[(size_t)(row0 + i) * N + col] = v;
      }
    }
  }
}

// ---------------- blockwise attention: one workgroup per (b, block, head) ----------------
// Q,K,V tiles 128x64 bf16 in LDS (ld=72: 144B rows, 16B-aligned, 2 lanes/bank frag reads).
// S = (QK^T)/8 in f32 LDS; softmax f32; P bf16 (unnormalized, ld=152); O = P*V * invSum.
__global__ __launch_bounds__(256) void attn_kernel(const s16* __restrict__ Q, const s16* __restrict__ K,
                                                   const s16* __restrict__ V, s16* __restrict__ O) {
  __shared__ s16   u_qkp[19456];       // qs[128][72] | ks[128][72]; later P[128][152]
  __shared__ s16   vs[128 * 72];
  __shared__ float Sb[128 * 132];
  __shared__ float invSum[128];

  const int tid = threadIdx.x;
  const int w = tid >> 6, l = tid & 63;
  const int lr = l & 15, lk = l >> 4;
  const int bid = blockIdx.x;                       // b*512 + n*16 + h
  const int b = bid >> 9;
  const int n = (bid >> 4) & 31;
  const int h = bid & 15;
  const size_t tokBase = (size_t)b * Tt + (size_t)n * BSs;
  const int colBase = h * HDd;

  s16* qs = u_qkp;
  s16* ks = u_qkp + 9216;
  s16* P  = u_qkp;                                  // [128][152]

  // stage Q,K,V tiles
#pragma unroll
  for (int t = 0; t < 4; ++t) {
    int s = t * 256 + tid;                          // 1024 (row, group-of-8) slots
    int r = s >> 3, g = s & 7;
    size_t gidx = (tokBase + r) * Cc + colBase + g * 8;
    int4v dq = *(const int4v*)&Q[gidx];
    int4v dk = *(const int4v*)&K[gidx];
    int4v dv = *(const int4v*)&V[gidx];
    *(int4v*)&qs[r * 72 + g * 8] = dq;
    *(int4v*)&ks[r * 72 + g * 8] = dk;
    *(int4v*)&vs[r * 72 + g * 8] = dv;
  }
  __syncthreads();

  // QK^T: wave w owns 32 query rows x 128 key cols = 2x8 16x16 tiles
  {
    f32x4 accS[2][8];
#pragma unroll
    for (int mt = 0; mt < 2; ++mt)
#pragma unroll
      for (int nt = 0; nt < 8; ++nt) accS[mt][nt] = (f32x4){0.f, 0.f, 0.f, 0.f};

#pragma unroll
    for (int st = 0; st < 2; ++st) {                // d = st*32 + lk*8 + e
      short8 aq[2], bk[8];
#pragma unroll
      for (int mt = 0; mt < 2; ++mt) {
        int row = w * 32 + mt * 16 + lr;
        aq[mt] = *(const short8*)&qs[row * 72 + st * 32 + lk * 8];
      }
#pragma unroll
      for (int nt = 0; nt < 8; ++nt) {
        int row = nt * 16 + lr;
        bk[nt] = *(const short8*)&ks[row * 72 + st * 32 + lk * 8];
      }
#pragma unroll
      for (int mt = 0; mt < 2; ++mt)
#pragma unroll
        for (int nt = 0; nt < 8; ++nt)
          accS[mt][nt] = __builtin_amdgcn_mfma_f32_16x16x32_bf16(aq[mt], bk[nt], accS[mt][nt], 0, 0, 0);
    }
    // logits = raw/8 (ref scales q,k by HD^-0.25 each; fold as exact *0.125 in f32)
#pragma unroll
    for (int mt = 0; mt < 2; ++mt)
#pragma unroll
      for (int nt = 0; nt < 8; ++nt)
#pragma unroll
        for (int i = 0; i < 4; ++i) {
          int row = w * 32 + mt * 16 + lk * 4 + i;
          int col = nt * 16 + lr;
          Sb[row * 132 + col] = accS[mt][nt][i] * 0.125f;
        }
  }
  __syncthreads();   // also: everyone done reading qs/ks before P overwrites them

  // softmax: 2 threads per row (64 elems each), combine via shfl_xor(1)
  {
    int r = tid >> 1, half = tid & 1;
    const float* srow = &Sb[r * 132 + half * 64];
    float m = srow[0];
#pragma unroll
    for (int j = 1; j < 64; ++j) m = fmaxf(m, srow[j]);
    m = fmaxf(m, __shfl_xor(m, 1));
    float sum = 0.f;
    uint32_t* prow = (uint32_t*)&P[r * 152 + half * 64];
#pragma unroll
    for (int j = 0; j < 32; ++j) {
      float e0 = __expf(srow[2 * j]     - m);
      float e1 = __expf(srow[2 * j + 1] - m);
      sum += e0 + e1;
      prow[j] = (uint32_t)(uint16_t)f2bf(e0) | ((uint32_t)(uint16_t)f2bf(e1) << 16);
    }
    sum += __shfl_xor(sum, 1);
    if (half == 0) invSum[r] = 1.0f / sum;
  }
  __syncthreads();

  // O = P * V: wave w owns 32 rows x 64 d = 2x4 tiles; V B-frags assembled by scalar LDS reads
  {
    f32x4 accO[2][4];
#pragma unroll
    for (int mt = 0; mt < 2; ++mt)
#pragma unroll
      for (int nt = 0; nt < 4; ++nt) accO[mt][nt] = (f32x4){0.f, 0.f, 0.f, 0.f};

#pragma unroll
    for (int st = 0; st < 4; ++st) {                // j = st*32 + lk*8 + e
      short8 ap[2], bv[4];
#pragma unroll
      for (int mt = 0; mt < 2; ++mt) {
        int row = w * 32 + mt * 16 + lr;
        ap[mt] = *(const short8*)&P[row * 152 + st * 32 + lk * 8];
      }
#pragma unroll
      for (int nt = 0; nt < 4; ++nt) {
        int d = nt * 16 + lr;
        short8 x;
#pragma unroll
        for (int e = 0; e < 8; ++e) {
          int j = st * 32 + lk * 8 + e;
          x[e] = vs[j * 72 + d];                    // V[j][d] -> B[k=j][n=d]
        }
        bv[nt] = x;
      }
#pragma unroll
      for (int mt = 0; mt < 2; ++mt)
#pragma unroll
        for (int nt = 0; nt < 4; ++nt)
          accO[mt][nt] = __builtin_amdgcn_mfma_f32_16x16x32_bf16(ap[mt], bv[nt], accO[mt][nt], 0, 0, 0);
    }

#pragma unroll
    for (int mt = 0; mt < 2; ++mt)
#pragma unroll
      for (int nt = 0; nt < 4; ++nt)
#pragma unroll
        for (int i = 0; i < 4; ++i) {
          int rl = w * 32 + mt * 16 + lk * 4 + i;
          int d = nt * 16 + lr;
          float v = accO[mt][nt][i] * invSum[rl];
          O[(tokBase + rl) * Cc + colBase + d] = f2bf(v);
        }
  }
}

// ---------------- host ----------------
extern "C" void kernel_launch(void* const* d_in, const int* in_sizes, int n_in,
                              void* d_out, int out_size, void* d_ws, size_t ws_size,
                              hipStream_t stream) {
  const float* x  = (const float*)d_in[0];
  const float* Wq = (const float*)d_in[1];
  const float* bq = (const float*)d_in[2];
  const float* Wk = (const float*)d_in[3];
  const float* Wv = (const float*)d_in[4];
  const float* bv = (const float*)d_in[5];
  const float* Wo = (const float*)d_in[6];
  const float* bo = (const float*)d_in[7];

  // ws layout (72 MB): xb 32M | 4 weights 2M each | Qb 32M.
  // K/V bf16 buffers live in d_out (64 MB) — consumed by attn BEFORE the
  // final GEMM overwrites d_out with the real f32 output (stream-ordered).
  if (ws_size < (size_t)75497472) return;   // clean fail instead of OOB crash
  char* ws = (char*)d_ws;
  s16* xb  = (s16*)(ws);
  s16* wqb = (s16*)(ws + 33554432);
  s16* wkb = (s16*)(ws + 35651584);
  s16* wvb = (s16*)(ws + 37748736);
  s16* wob = (s16*)(ws + 39845888);
  s16* Qb  = (s16*)(ws + 41943040);
  s16* Kb  = (s16*)((char*)d_out);
  s16* Vb  = (s16*)((char*)d_out + 33554432);

  // 1) convert inputs to bf16
  cvt_x<<<8192, 256, 0, stream>>>(x, xb);                       // 16.7M elems
  cvt_w<<<2048, 256, 0, stream>>>(Wq, Wk, Wv, Wo, wqb, wkb, wvb, wob);

  // 2) projections: q = x Wq^T + bq ; k = x Wk^T ; v = x Wv^T + bv
  dim3 gg(Cc / 128, MTOT / 128);                                 // (8,128)
  gemm_bt<true><<<gg, 256, 0, stream>>>(xb, wqb, bq,      Qb, MTOT, Cc, Cc);
  gemm_bt<true><<<gg, 256, 0, stream>>>(xb, wkb, nullptr, Kb, MTOT, Cc, Cc);
  gemm_bt<true><<<gg, 256, 0, stream>>>(xb, wvb, bv,      Vb, MTOT, Cc, Cc);

  // 3) blockwise attention; O overwrites Qb (block-disjoint, Q staged to LDS first)
  attn_kernel<<<Bb * NBn * Hh, 256, 0, stream>>>(Qb, Kb, Vb, Qb);

  // 4) out = O Wo^T + bo (f32 out); overwrites the K/V scratch in d_out
  gemm_bt<false><<<gg, 256, 0, stream>>>(Qb, wob, bo, (float*)d_out, MTOT, Cc, Cc);
}

// Round 5
// 344.670 us; speedup vs baseline: 1.2623x; 1.2623x over previous
//
#include <hip/hip_runtime.h>
#include <stdint.h>

// Problem: B=4, T=4096, C=1024, H=16, HD=64, NBLOCKS=32, BSIZE=128
#define Bb   4
#define Tt   4096
#define Cc   1024
#define Hh   16
#define HDd  64
#define NBn  32
#define BSs  128
#define MTOT (Bb*Tt)   // 16384 rows

typedef short s16;
typedef __attribute__((ext_vector_type(8))) short  short8;   // 8 bf16 (4 VGPRs)
typedef __attribute__((ext_vector_type(4))) float  f32x4;    // MFMA C/D frag
typedef __attribute__((ext_vector_type(4))) int    int4v;

__device__ __forceinline__ s16 f2bf(float f) {   // f32 -> bf16, RNE
  union { float f; uint32_t u; } c; c.f = f;
  return (s16)((c.u + 0x7fffu + ((c.u >> 16) & 1u)) >> 16);
}

typedef const __attribute__((address_space(1))) void* gas_p;
typedef __attribute__((address_space(3))) void*       las_p;
__device__ __forceinline__ void lds16(const void* g, void* l) {
  // async global->LDS; LDS dest MUST be wave-uniform (HW adds lane*16)
  __builtin_amdgcn_global_load_lds((gas_p)g, (las_p)l, 16, 0, 0);
}

// ---------------- f32 -> bf16 conversion kernels ----------------
__global__ __launch_bounds__(256) void cvt_x(const float* __restrict__ in, s16* __restrict__ out) {
  int i = blockIdx.x * 256 + threadIdx.x;
  const f32x4* p = (const f32x4*)(in + (size_t)i * 8);
  f32x4 a = p[0], b = p[1];
  short8 o;
  o[0]=f2bf(a[0]); o[1]=f2bf(a[1]); o[2]=f2bf(a[2]); o[3]=f2bf(a[3]);
  o[4]=f2bf(b[0]); o[5]=f2bf(b[1]); o[6]=f2bf(b[2]); o[7]=f2bf(b[3]);
  *(short8*)(out + (size_t)i * 8) = o;
}

__global__ __launch_bounds__(256) void cvt_w(const float* w0, const float* w1,
                                             const float* w2, const float* w3,
                                             s16* o0, s16* o1, s16* o2, s16* o3) {
  int i = blockIdx.x * 256 + threadIdx.x;
  int which = i >> 17;
  int j = i & 131071;
  const float* w = which == 0 ? w0 : which == 1 ? w1 : which == 2 ? w2 : w3;
  s16*         o = which == 0 ? o0 : which == 1 ? o1 : which == 2 ? o2 : o3;
  const f32x4* p = (const f32x4*)(w + (size_t)j * 8);
  f32x4 a = p[0], b = p[1];
  short8 v;
  v[0]=f2bf(a[0]); v[1]=f2bf(a[1]); v[2]=f2bf(a[2]); v[3]=f2bf(a[3]);
  v[4]=f2bf(b[0]); v[5]=f2bf(b[1]); v[6]=f2bf(b[2]); v[7]=f2bf(b[3]);
  *(short8*)(o + (size_t)j * 8) = v;
}

// ---------------- bt-GEMM: C[m,n] = sum_k A[m,k]*W[n,k] (+bias[n]) ----------------
// 128x128 tile, BK=64, 4 waves, 4x4 16x16x32 frags/wave, global_load_lds w=16.
// k-group XOR swizzle: LDS slot (r,gp) holds k-group kg = gp ^ (r&7) (T2-style),
// applied via pre-swizzled GLOBAL src (LDS dest of global_load_lds stays linear).
// XCD chunked swizzle: XCD k owns y in [16k,16k+16), 8-row chunks, x-fast within.
// OUT_BF16: segmented epilogue (Q|K|V by nBase>>10), LDS-staged for coalesced stores.
template <bool OUT_BF16, int NX>
__global__ __launch_bounds__(256) void gemm_bt(const s16* __restrict__ A, const s16* __restrict__ Bm,
                                               const float* b0, const float* b1, const float* b2,
                                               void* o0, void* o1, void* o2) {
  __shared__ s16 smem[17408];       // 34816 B: As|Bs (32 KB) in k-loop, Cs[128][136] in epilogue
  s16* As = smem;
  s16* Bs = smem + 8192;

  const int tid = threadIdx.x;
  const int w = tid >> 6, l = tid & 63;
  const int lr = l & 15, lk = l >> 4;
  const int wr = w >> 1, wc = w & 1;

  // XCD-aware chunked swizzle (1D grid, NX*128 blocks, divisible by 8)
  const int lid = blockIdx.x;
  const int xcd = lid & 7, sl = lid >> 3;
  const int per_row = NX * 8;
  const int chunk = sl / per_row;
  const int rem = sl - chunk * per_row;
  const int yy = rem / NX;
  const int xx = rem - yy * NX;
  const int mBase = (xcd * 16 + chunk * 8 + yy) * 128;
  const int nBase = xx * 128;

  f32x4 acc[4][4];
#pragma unroll
  for (int i = 0; i < 4; ++i)
#pragma unroll
    for (int j = 0; j < 4; ++j) acc[i][j] = (f32x4){0.f, 0.f, 0.f, 0.f};

  for (int k0 = 0; k0 < Cc; k0 += 64) {
    // stage 128x64 A and B tiles: 1024 slots of 16B each, 4 per thread.
    // LDS dest is WAVE-UNIFORM (t*256 + w*64); HW adds lane*16. Global src per-lane.
#pragma unroll
    for (int t = 0; t < 4; ++t) {
      int s = t * 256 + tid;
      int r = s >> 3, gp = s & 7;
      int kg = gp ^ (r & 7);
      lds16(A  + (size_t)(mBase + r) * Cc + (k0 + kg * 8), &As[(t * 256 + w * 64) * 8]);
      lds16(Bm + (size_t)(nBase + r) * Cc + (k0 + kg * 8), &Bs[(t * 256 + w * 64) * 8]);
    }
    __syncthreads();

#pragma unroll
    for (int kk = 0; kk < 2; ++kk) {
      short8 af[4], bf[4];
#pragma unroll
      for (int mt = 0; mt < 4; ++mt) {
        int row = wr * 64 + mt * 16 + lr;
        af[mt] = *(const short8*)&As[row * 64 + (((kk * 4 + lk) ^ (row & 7)) * 8)];
      }
#pragma unroll
      for (int nt = 0; nt < 4; ++nt) {
        int row = wc * 64 + nt * 16 + lr;
        bf[nt] = *(const short8*)&Bs[row * 64 + (((kk * 4 + lk) ^ (row & 7)) * 8)];
      }
#pragma unroll
      for (int mt = 0; mt < 4; ++mt)
#pragma unroll
        for (int nt = 0; nt < 4; ++nt)
          acc[mt][nt] = __builtin_amdgcn_mfma_f32_16x16x32_bf16(af[mt], bf[nt], acc[mt][nt], 0, 0, 0);
    }
    __syncthreads();
  }

  if (OUT_BF16) {
    // segmented (Q|K|V), LDS-staged coalesced bf16 store
    const int seg = nBase >> 10;
    const float* bias = seg == 0 ? b0 : (seg == 1 ? b1 : b2);
    s16* outp = (s16*)(seg == 0 ? o0 : (seg == 1 ? o1 : o2));
    const int colL = nBase & 1023;
    s16* Cs = smem;   // [128][136]
#pragma unroll
    for (int nt = 0; nt < 4; ++nt) {
      int col = wc * 64 + nt * 16 + lr;
      float bb = bias ? bias[colL + col] : 0.0f;
#pragma unroll
      for (int mt = 0; mt < 4; ++mt) {
        int row0 = wr * 64 + mt * 16 + lk * 4;
#pragma unroll
        for (int i = 0; i < 4; ++i)
          Cs[(row0 + i) * 136 + col] = f2bf(acc[mt][nt][i] + bb);
      }
    }
    __syncthreads();
    // full tile = 128 rows x 128 cols = 2048 slots of 8 shorts -> 8 iters of 256 thr
#pragma unroll
    for (int t = 0; t < 8; ++t) {
      int s = t * 256 + tid;
      int r = s >> 4, g = s & 15;
      *(short8*)&outp[(size_t)(mBase + r) * 1024 + colL + g * 8] =
          *(const short8*)&Cs[r * 136 + g * 8];
    }
  } else {
    // f32 direct store (16 lanes x 4B = full 64B lines already)
    float* outp = (float*)o0;
#pragma unroll
    for (int nt = 0; nt < 4; ++nt) {
      int col = nBase + wc * 64 + nt * 16 + lr;
      float bb = b0[col];
#pragma unroll
      for (int mt = 0; mt < 4; ++mt) {
        int row0 = mBase + wr * 64 + mt * 16 + lk * 4;
#pragma unroll
        for (int i = 0; i < 4; ++i)
          outp[(size_t)(row0 + i) * 1024 + col] = acc[mt][nt][i] + bb;
      }
    }
  }
}

// ---------------- blockwise attention: one workgroup per (b, block, head) ----------------
// qs/ks [128][72] bf16; V stored TRANSPOSED vsT[d][j] (ld=136) with j-group XOR swizzle
// jg ^= (d&7)^(d>>3) -> staging scalar writes ~2-way free, PV B-frags are ds_read_b128.
// Softmax fully in-register (row = 16-lane lr group: 4x shfl_xor); P bf16 overlays qs/ks.
__global__ __launch_bounds__(256) void attn_kernel(const s16* __restrict__ Q, const s16* __restrict__ K,
                                                   const s16* __restrict__ V, s16* __restrict__ O) {
  __shared__ s16   u_qkp[19456];       // qs[128][72] | ks[128][72]; later P[128][152]
  __shared__ s16   vsT[64 * 136];      // 17408 B
  __shared__ float invSum[128];

  const int tid = threadIdx.x;
  const int w = tid >> 6, l = tid & 63;
  const int lr = l & 15, lk = l >> 4;
  const int bid = blockIdx.x;                       // b*512 + n*16 + h
  const int b = bid >> 9;
  const int n = (bid >> 4) & 31;
  const int h = bid & 15;
  const size_t tokBase = (size_t)b * Tt + (size_t)n * BSs;
  const int colBase = h * HDd;

  s16* qs = u_qkp;
  s16* ks = u_qkp + 9216;
  s16* P  = u_qkp;                                  // [128][152]

  // stage Q,K row-major; V transposed+swizzled
#pragma unroll
  for (int t = 0; t < 4; ++t) {
    int s = t * 256 + tid;
    int r = s >> 3, g = s & 7;
    size_t gidx = (tokBase + r) * Cc + colBase + g * 8;
    int4v  dq = *(const int4v*)&Q[gidx];
    int4v  dk = *(const int4v*)&K[gidx];
    short8 dv = *(const short8*)&V[gidx];
    *(int4v*)&qs[r * 72 + g * 8] = dq;
    *(int4v*)&ks[r * 72 + g * 8] = dk;
    int rg = r >> 3, rl = r & 7;
#pragma unroll
    for (int e = 0; e < 8; ++e) {
      int d = g * 8 + e;                            // d&7 == e, d>>3 == g
      vsT[d * 136 + ((rg ^ e ^ g) << 3) + rl] = dv[e];
    }
  }
  __syncthreads();

  // QK^T: wave w owns 32 query rows x 128 key cols = 2x8 16x16 tiles
  f32x4 accS[2][8];
#pragma unroll
  for (int mt = 0; mt < 2; ++mt)
#pragma unroll
    for (int nt = 0; nt < 8; ++nt) accS[mt][nt] = (f32x4){0.f, 0.f, 0.f, 0.f};

#pragma unroll
  for (int st = 0; st < 2; ++st) {
    short8 aq[2], bk[8];
#pragma unroll
    for (int mt = 0; mt < 2; ++mt)
      aq[mt] = *(const short8*)&qs[(w * 32 + mt * 16 + lr) * 72 + st * 32 + lk * 8];
#pragma unroll
    for (int nt = 0; nt < 8; ++nt)
      bk[nt] = *(const short8*)&ks[(nt * 16 + lr) * 72 + st * 32 + lk * 8];
#pragma unroll
    for (int mt = 0; mt < 2; ++mt)
#pragma unroll
      for (int nt = 0; nt < 8; ++nt)
        accS[mt][nt] = __builtin_amdgcn_mfma_f32_16x16x32_bf16(aq[mt], bk[nt], accS[mt][nt], 0, 0, 0);
  }

  // in-register softmax: row (w,mt,lk,i) spread across 16 lanes (lr) x 8 frags (nt).
  // logits = raw/8 -> p = exp((raw - rawmax) * 0.125)
#pragma unroll
  for (int mt = 0; mt < 2; ++mt)
#pragma unroll
    for (int i = 0; i < 4; ++i) {
      float m = accS[mt][0][i];
#pragma unroll
      for (int nt = 1; nt < 8; ++nt) m = fmaxf(m, accS[mt][nt][i]);
      m = fmaxf(m, __shfl_xor(m, 1));
      m = fmaxf(m, __shfl_xor(m, 2));
      m = fmaxf(m, __shfl_xor(m, 4));
      m = fmaxf(m, __shfl_xor(m, 8));
      float sum = 0.f;
#pragma unroll
      for (int nt = 0; nt < 8; ++nt) {
        float p = __expf((accS[mt][nt][i] - m) * 0.125f);
        sum += p;
        accS[mt][nt][i] = p;
      }
      sum += __shfl_xor(sum, 1);
      sum += __shfl_xor(sum, 2);
      sum += __shfl_xor(sum, 4);
      sum += __shfl_xor(sum, 8);
      if (lr == 0) invSum[w * 32 + mt * 16 + lk * 4 + i] = 1.0f / sum;
    }
  __syncthreads();   // all waves done reading qs/ks before P overwrites them

  // P (unnormalized exp) -> LDS bf16
#pragma unroll
  for (int mt = 0; mt < 2; ++mt)
#pragma unroll
    for (int nt = 0; nt < 8; ++nt)
#pragma unroll
      for (int i = 0; i < 4; ++i)
        P[(w * 32 + mt * 16 + lk * 4 + i) * 152 + nt * 16 + lr] = f2bf(accS[mt][nt][i]);
  __syncthreads();

  // O = P * V: all-vector LDS reads now (A from P rows, B from vsT)
  f32x4 accO[2][4];
#pragma unroll
  for (int mt = 0; mt < 2; ++mt)
#pragma unroll
    for (int nt = 0; nt < 4; ++nt) accO[mt][nt] = (f32x4){0.f, 0.f, 0.f, 0.f};

#pragma unroll
  for (int st = 0; st < 4; ++st) {
    short8 ap[2], bv[4];
#pragma unroll
    for (int mt = 0; mt < 2; ++mt)
      ap[mt] = *(const short8*)&P[(w * 32 + mt * 16 + lr) * 152 + st * 32 + lk * 8];
#pragma unroll
    for (int nt = 0; nt < 4; ++nt) {
      int d = nt * 16 + lr;
      bv[nt] = *(const short8*)&vsT[d * 136 + ((((st * 4 + lk) ^ (d & 7) ^ (d >> 3))) << 3)];
    }
#pragma unroll
    for (int mt = 0; mt < 2; ++mt)
#pragma unroll
      for (int nt = 0; nt < 4; ++nt)
        accO[mt][nt] = __builtin_amdgcn_mfma_f32_16x16x32_bf16(ap[mt], bv[nt], accO[mt][nt], 0, 0, 0);
  }

#pragma unroll
  for (int mt = 0; mt < 2; ++mt)
#pragma unroll
    for (int nt = 0; nt < 4; ++nt)
#pragma unroll
      for (int i = 0; i < 4; ++i) {
        int rl = w * 32 + mt * 16 + lk * 4 + i;
        int d = nt * 16 + lr;
        float v = accO[mt][nt][i] * invSum[rl];
        O[(tokBase + rl) * Cc + colBase + d] = f2bf(v);
      }
}

// ---------------- host ----------------
extern "C" void kernel_launch(void* const* d_in, const int* in_sizes, int n_in,
                              void* d_out, int out_size, void* d_ws, size_t ws_size,
                              hipStream_t stream) {
  const float* x  = (const float*)d_in[0];
  const float* Wq = (const float*)d_in[1];
  const float* bq = (const float*)d_in[2];
  const float* Wk = (const float*)d_in[3];
  const float* Wv = (const float*)d_in[4];
  const float* bv = (const float*)d_in[5];
  const float* Wo = (const float*)d_in[6];
  const float* bo = (const float*)d_in[7];

  // ws layout (72 MB): xb 32M | wq|wk|wv (6M contiguous = fused 3072x1024) | wo 2M | Qb 32M.
  // K/V bf16 live in d_out (64 MB), consumed by attn before the final GEMM overwrites it.
  if (ws_size < (size_t)75497472) return;
  char* ws = (char*)d_ws;
  s16* xb  = (s16*)(ws);
  s16* wqb = (s16*)(ws + 33554432);
  s16* wkb = (s16*)(ws + 35651584);
  s16* wvb = (s16*)(ws + 37748736);
  s16* wob = (s16*)(ws + 39845888);
  s16* Qb  = (s16*)(ws + 41943040);
  s16* Kb  = (s16*)((char*)d_out);
  s16* Vb  = (s16*)((char*)d_out + 33554432);

  // 1) convert inputs to bf16
  cvt_x<<<8192, 256, 0, stream>>>(x, xb);
  cvt_w<<<2048, 256, 0, stream>>>(Wq, Wk, Wv, Wo, wqb, wkb, wvb, wob);

  // 2) fused QKV projection: [16384x1024] x [3072x1024]^T -> Qb|Kb|Vb (segmented)
  gemm_bt<true, 24><<<24 * 128, 256, 0, stream>>>(xb, wqb, bq, nullptr, bv, Qb, Kb, Vb);

  // 3) blockwise attention; O overwrites Qb (block-disjoint, Q staged to LDS first)
  attn_kernel<<<Bb * NBn * Hh, 256, 0, stream>>>(Qb, Kb, Vb, Qb);

  // 4) out = O Wo^T + bo (f32), overwrites K/V scratch in d_out
  gemm_bt<false, 8><<<8 * 128, 256, 0, stream>>>(Qb, wob, bo, bo, bo, (float*)d_out, nullptr, nullptr);
}

// Round 6
// 316.967 us; speedup vs baseline: 1.3726x; 1.0874x over previous
//
#include <hip/hip_runtime.h>
#include <stdint.h>

// Problem: B=4, T=4096, C=1024, H=16, HD=64, NBLOCKS=32, BSIZE=128
#define Bb   4
#define Tt   4096
#define Cc   1024
#define Hh   16
#define HDd  64
#define NBn  32
#define BSs  128
#define MTOT (Bb*Tt)   // 16384 rows

typedef short s16;
typedef __attribute__((ext_vector_type(8))) short  short8;   // 8 bf16 (4 VGPRs)
typedef __attribute__((ext_vector_type(4))) float  f32x4;    // MFMA C/D frag
typedef __attribute__((ext_vector_type(4))) int    int4v;

__device__ __forceinline__ s16 f2bf(float f) {   // f32 -> bf16, RNE
  union { float f; uint32_t u; } c; c.f = f;
  return (s16)((c.u + 0x7fffu + ((c.u >> 16) & 1u)) >> 16);
}

typedef const __attribute__((address_space(1))) void* gas_p;
typedef __attribute__((address_space(3))) void*       las_p;
__device__ __forceinline__ void lds16(const void* g, void* l) {
  // async global->LDS; LDS dest must be wave-uniform (HW adds lane*16)
  __builtin_amdgcn_global_load_lds((gas_p)g, (las_p)l, 16, 0, 0);
}

// ---------------- f32 -> bf16 conversion kernels ----------------
__global__ __launch_bounds__(256) void cvt_x(const float* __restrict__ in, s16* __restrict__ out) {
  int i = blockIdx.x * 256 + threadIdx.x;
  const f32x4* p = (const f32x4*)(in + (size_t)i * 8);
  f32x4 a = p[0], b = p[1];
  short8 o;
  o[0]=f2bf(a[0]); o[1]=f2bf(a[1]); o[2]=f2bf(a[2]); o[3]=f2bf(a[3]);
  o[4]=f2bf(b[0]); o[5]=f2bf(b[1]); o[6]=f2bf(b[2]); o[7]=f2bf(b[3]);
  *(short8*)(out + (size_t)i * 8) = o;
}

__global__ __launch_bounds__(256) void cvt_w(const float* w0, const float* w1,
                                             const float* w2, const float* w3,
                                             s16* o0, s16* o1, s16* o2, s16* o3) {
  int i = blockIdx.x * 256 + threadIdx.x;
  int which = i >> 17;
  int j = i & 131071;
  const float* w = which == 0 ? w0 : which == 1 ? w1 : which == 2 ? w2 : w3;
  s16*         o = which == 0 ? o0 : which == 1 ? o1 : which == 2 ? o2 : o3;
  const f32x4* p = (const f32x4*)(w + (size_t)j * 8);
  f32x4 a = p[0], b = p[1];
  short8 v;
  v[0]=f2bf(a[0]); v[1]=f2bf(a[1]); v[2]=f2bf(a[2]); v[3]=f2bf(a[3]);
  v[4]=f2bf(b[0]); v[5]=f2bf(b[1]); v[6]=f2bf(b[2]); v[7]=f2bf(b[3]);
  *(short8*)(o + (size_t)j * 8) = v;
}

// ---------------- 256x256 multi-phase bt-GEMM: C[m,n] = sum_k A[m,k]*W[n,k] (+bias) ----
// 8 waves (2m x 4n), per-wave 128x64 out = 8x4 16x16 frags. BK=64, K=1024 (16 K-tiles),
// 2-slot LDS double buffer (128 KiB). Per K-tile, 4 phases:
//   phase0: issue all 8 global_load_lds of K-tile kt+1 into slot c^1; load B-frags (8 reads,
//           whole K-tile); read A-quadrant 0; setprio1; 16 MFMA; setprio0; s_barrier
//   phase1-3: read A-quadrant q; 16 MFMA; (q==3: s_waitcnt vmcnt(0)); s_barrier
// vmcnt(0) only once per K-tile, issued ~3 phases after the loads -> near-free.
// Safety: slot c^1 is written only after the barrier that follows its last reader's
// MFMAs (which consumed all ds_read data; compiler-inserted lgkmcnt precedes them).
// LDS element (row,k) of a tile lives at [row*64 + ((k>>3)^(row&7))*8 + (k&7)]
// (row-XOR k-group swizzle, applied on the global src; measured conflict-free-ish r5).
template <bool OUT_BF16, int NXT>
__global__ __launch_bounds__(512, 2) void gemm256(const s16* __restrict__ Ag, const s16* __restrict__ Bg,
                                                  const float* b0, const float* b1, const float* b2,
                                                  void* o0, void* o1, void* o2) {
  __shared__ s16 smem[65536];   // 128 KiB: As[2][16384] | Bs[2][16384]

  const int tid = threadIdx.x;
  const int w = tid >> 6, l = tid & 63;
  const int lr = l & 15, lk = l >> 4;
  const int wm = w >> 2, wn = w & 3;

  // XCD-chunked block swizzle: xcd owns 8 m-tiles x NXT n-tiles (grid = 8*8*NXT)
  const int lid = blockIdx.x;
  const int xcd = lid & 7, s0 = lid >> 3;
  const int my = xcd * 8 + s0 / NXT;
  const int nx = s0 - (s0 / NXT) * NXT;
  const int mBase = my * 256, nBase = nx * 256;

  f32x4 acc[8][4];
#pragma unroll
  for (int i = 0; i < 8; ++i)
#pragma unroll
    for (int j = 0; j < 4; ++j) acc[i][j] = (f32x4){0.f, 0.f, 0.f, 0.f};

  // ---- staging helper: 8 global_load_lds (4 A + 4 B), 512 lanes x 16 B each ----
  auto stage_tile = [&](int slot, int k0) {
    s16* Asl = smem + slot * 16384;
    s16* Bsl = smem + 32768 + slot * 16384;
#pragma unroll
    for (int L = 0; L < 4; ++L) {
      int s = L * 512 + tid;
      int r = s >> 3;
      int kg = (s & 7) ^ (r & 7);
      int wbase = (L * 512 + (tid & ~63)) * 8;   // wave-uniform LDS dest
      lds16(Ag + (size_t)(mBase + r) * Cc + (k0 + kg * 8), Asl + wbase);
      lds16(Bg + (size_t)(nBase + r) * Cc + (k0 + kg * 8), Bsl + wbase);
    }
  };

  // prologue: K-tile 0 -> slot 0 (full drain is fine here)
  stage_tile(0, 0);
  __syncthreads();

  for (int kt = 0; kt < 16; ++kt) {
    const int c = kt & 1;
    const s16* Asc = smem + c * 16384;
    const s16* Bsc = smem + 32768 + c * 16384;

    // phase 0 head: prefetch next K-tile into the other slot
    if (kt < 15) stage_tile(c ^ 1, (kt + 1) * 64);

    // B-frags for the whole K-tile (live in regs across all 4 phases)
    short8 bk[4][2];
#pragma unroll
    for (int nt = 0; nt < 4; ++nt)
#pragma unroll
      for (int kk = 0; kk < 2; ++kk) {
        int row = wn * 64 + nt * 16 + lr;
        bk[nt][kk] = *(const short8*)&Bsc[row * 64 + (((kk * 4 + lk) ^ (lr & 7)) * 8)];
      }

#pragma unroll
    for (int q = 0; q < 4; ++q) {
      short8 af[2][2];
#pragma unroll
      for (int mt2 = 0; mt2 < 2; ++mt2)
#pragma unroll
        for (int kk = 0; kk < 2; ++kk) {
          int row = wm * 128 + (q * 2 + mt2) * 16 + lr;
          af[mt2][kk] = *(const short8*)&Asc[row * 64 + (((kk * 4 + lk) ^ (lr & 7)) * 8)];
        }
      __builtin_amdgcn_s_setprio(1);
#pragma unroll
      for (int mt2 = 0; mt2 < 2; ++mt2)
#pragma unroll
        for (int nt = 0; nt < 4; ++nt)
#pragma unroll
          for (int kk = 0; kk < 2; ++kk)
            acc[q * 2 + mt2][nt] = __builtin_amdgcn_mfma_f32_16x16x32_bf16(
                af[mt2][kk], bk[nt][kk], acc[q * 2 + mt2][nt], 0, 0, 0);
      __builtin_amdgcn_s_setprio(0);
      if (q == 3) asm volatile("s_waitcnt vmcnt(0)" ::: "memory");   // once per K-tile
      __builtin_amdgcn_sched_barrier(0);
      asm volatile("s_barrier" ::: "memory");
      __builtin_amdgcn_sched_barrier(0);
    }
  }

  if (OUT_BF16) {
    // segmented (Q|K|V by nBase>>10; 256-tile never straddles a 1024 boundary),
    // LDS-staged coalesced bf16 stores; two row-half passes (Cs = [128][264])
    const int seg = nBase >> 10;
    const float* bias = seg == 0 ? b0 : (seg == 1 ? b1 : b2);
    s16* outp = (s16*)(seg == 0 ? o0 : (seg == 1 ? o1 : o2));
    const int colL = nBase & 1023;
    s16* Cs = smem;
#pragma unroll
    for (int h = 0; h < 2; ++h) {
      if (wm == h) {
#pragma unroll
        for (int nt = 0; nt < 4; ++nt) {
          int col = wn * 64 + nt * 16 + lr;
          float bb = bias ? bias[colL + col] : 0.0f;
#pragma unroll
          for (int mt = 0; mt < 8; ++mt) {
            int r0 = mt * 16 + lk * 4;
#pragma unroll
            for (int i = 0; i < 4; ++i)
              Cs[(r0 + i) * 264 + col] = f2bf(acc[mt][nt][i] + bb);
          }
        }
      }
      __syncthreads();
      // 128 rows x 256 cols = 4096 short8 slots -> 8 iters of 512 threads
#pragma unroll
      for (int t = 0; t < 8; ++t) {
        int s2 = t * 512 + tid;
        int r = s2 >> 5, g = s2 & 31;
        *(short8*)&outp[(size_t)(mBase + h * 128 + r) * 1024 + colL + g * 8] =
            *(const short8*)&Cs[r * 264 + g * 8];
      }
      __syncthreads();
    }
  } else {
    // f32 direct store (16 lanes x 4 B consecutive = full lines)
    float* outp = (float*)o0;
#pragma unroll
    for (int nt = 0; nt < 4; ++nt) {
      int col = nBase + wn * 64 + nt * 16 + lr;
      float bb = b0[col];
#pragma unroll
      for (int mt = 0; mt < 8; ++mt) {
        int row0 = mBase + wm * 128 + mt * 16 + lk * 4;
#pragma unroll
        for (int i = 0; i < 4; ++i)
          outp[(size_t)(row0 + i) * 1024 + col] = acc[mt][nt][i] + bb;
      }
    }
  }
}

// ---------------- blockwise attention: one workgroup per (b, block, head) ----------------
// qs/ks [128][72] bf16; V stored TRANSPOSED vsT[d][j] (ld=136) with j-group XOR swizzle
// jg ^= (d&7)^(d>>3) -> staging scalar writes ~2-way free, PV B-frags are ds_read_b128.
// Softmax fully in-register (row = 16-lane lr group: 4x shfl_xor); P bf16 overlays qs/ks.
__global__ __launch_bounds__(256) void attn_kernel(const s16* __restrict__ Q, const s16* __restrict__ K,
                                                   const s16* __restrict__ V, s16* __restrict__ O) {
  __shared__ s16   u_qkp[19456];       // qs[128][72] | ks[128][72]; later P[128][152]
  __shared__ s16   vsT[64 * 136];      // 17408 B
  __shared__ float invSum[128];

  const int tid = threadIdx.x;
  const int w = tid >> 6, l = tid & 63;
  const int lr = l & 15, lk = l >> 4;
  const int bid = blockIdx.x;                       // b*512 + n*16 + h
  const int b = bid >> 9;
  const int n = (bid >> 4) & 31;
  const int h = bid & 15;
  const size_t tokBase = (size_t)b * Tt + (size_t)n * BSs;
  const int colBase = h * HDd;

  s16* qs = u_qkp;
  s16* ks = u_qkp + 9216;
  s16* P  = u_qkp;                                  // [128][152]

  // stage Q,K row-major; V transposed+swizzled
#pragma unroll
  for (int t = 0; t < 4; ++t) {
    int s = t * 256 + tid;
    int r = s >> 3, g = s & 7;
    size_t gidx = (tokBase + r) * Cc + colBase + g * 8;
    int4v  dq = *(const int4v*)&Q[gidx];
    int4v  dk = *(const int4v*)&K[gidx];
    short8 dv = *(const short8*)&V[gidx];
    *(int4v*)&qs[r * 72 + g * 8] = dq;
    *(int4v*)&ks[r * 72 + g * 8] = dk;
    int rg = r >> 3, rl = r & 7;
#pragma unroll
    for (int e = 0; e < 8; ++e) {
      int d = g * 8 + e;                            // d&7 == e, d>>3 == g
      vsT[d * 136 + ((rg ^ e ^ g) << 3) + rl] = dv[e];
    }
  }
  __syncthreads();

  // QK^T: wave w owns 32 query rows x 128 key cols = 2x8 16x16 tiles
  f32x4 accS[2][8];
#pragma unroll
  for (int mt = 0; mt < 2; ++mt)
#pragma unroll
    for (int nt = 0; nt < 8; ++nt) accS[mt][nt] = (f32x4){0.f, 0.f, 0.f, 0.f};

#pragma unroll
  for (int st = 0; st < 2; ++st) {
    short8 aq[2], bk[8];
#pragma unroll
    for (int mt = 0; mt < 2; ++mt)
      aq[mt] = *(const short8*)&qs[(w * 32 + mt * 16 + lr) * 72 + st * 32 + lk * 8];
#pragma unroll
    for (int nt = 0; nt < 8; ++nt)
      bk[nt] = *(const short8*)&ks[(nt * 16 + lr) * 72 + st * 32 + lk * 8];
#pragma unroll
    for (int mt = 0; mt < 2; ++mt)
#pragma unroll
      for (int nt = 0; nt < 8; ++nt)
        accS[mt][nt] = __builtin_amdgcn_mfma_f32_16x16x32_bf16(aq[mt], bk[nt], accS[mt][nt], 0, 0, 0);
  }

  // in-register softmax: row (w,mt,lk,i) spread across 16 lanes (lr) x 8 frags (nt).
  // logits = raw/8 -> p = exp((raw - rawmax) * 0.125)
#pragma unroll
  for (int mt = 0; mt < 2; ++mt)
#pragma unroll
    for (int i = 0; i < 4; ++i) {
      float m = accS[mt][0][i];
#pragma unroll
      for (int nt = 1; nt < 8; ++nt) m = fmaxf(m, accS[mt][nt][i]);
      m = fmaxf(m, __shfl_xor(m, 1));
      m = fmaxf(m, __shfl_xor(m, 2));
      m = fmaxf(m, __shfl_xor(m, 4));
      m = fmaxf(m, __shfl_xor(m, 8));
      float sum = 0.f;
#pragma unroll
      for (int nt = 0; nt < 8; ++nt) {
        float p = __expf((accS[mt][nt][i] - m) * 0.125f);
        sum += p;
        accS[mt][nt][i] = p;
      }
      sum += __shfl_xor(sum, 1);
      sum += __shfl_xor(sum, 2);
      sum += __shfl_xor(sum, 4);
      sum += __shfl_xor(sum, 8);
      if (lr == 0) invSum[w * 32 + mt * 16 + lk * 4 + i] = 1.0f / sum;
    }
  __syncthreads();   // all waves done reading qs/ks before P overwrites them

  // P (unnormalized exp) -> LDS bf16
#pragma unroll
  for (int mt = 0; mt < 2; ++mt)
#pragma unroll
    for (int nt = 0; nt < 8; ++nt)
#pragma unroll
      for (int i = 0; i < 4; ++i)
        P[(w * 32 + mt * 16 + lk * 4 + i) * 152 + nt * 16 + lr] = f2bf(accS[mt][nt][i]);
  __syncthreads();

  // O = P * V: all-vector LDS reads now (A from P rows, B from vsT)
  f32x4 accO[2][4];
#pragma unroll
  for (int mt = 0; mt < 2; ++mt)
#pragma unroll
    for (int nt = 0; nt < 4; ++nt) accO[mt][nt] = (f32x4){0.f, 0.f, 0.f, 0.f};

#pragma unroll
  for (int st = 0; st < 4; ++st) {
    short8 ap[2], bv[4];
#pragma unroll
    for (int mt = 0; mt < 2; ++mt)
      ap[mt] = *(const short8*)&P[(w * 32 + mt * 16 + lr) * 152 + st * 32 + lk * 8];
#pragma unroll
    for (int nt = 0; nt < 4; ++nt) {
      int d = nt * 16 + lr;
      bv[nt] = *(const short8*)&vsT[d * 136 + ((((st * 4 + lk) ^ (d & 7) ^ (d >> 3))) << 3)];
    }
#pragma unroll
    for (int mt = 0; mt < 2; ++mt)
#pragma unroll
      for (int nt = 0; nt < 4; ++nt)
        accO[mt][nt] = __builtin_amdgcn_mfma_f32_16x16x32_bf16(ap[mt], bv[nt], accO[mt][nt], 0, 0, 0);
  }

#pragma unroll
  for (int mt = 0; mt < 2; ++mt)
#pragma unroll
    for (int nt = 0; nt < 4; ++nt)
#pragma unroll
      for (int i = 0; i < 4; ++i) {
        int rl = w * 32 + mt * 16 + lk * 4 + i;
        int d = nt * 16 + lr;
        float v = accO[mt][nt][i] * invSum[rl];
        O[(tokBase + rl) * Cc + colBase + d] = f2bf(v);
      }
}

// ---------------- host ----------------
extern "C" void kernel_launch(void* const* d_in, const int* in_sizes, int n_in,
                              void* d_out, int out_size, void* d_ws, size_t ws_size,
                              hipStream_t stream) {
  const float* x  = (const float*)d_in[0];
  const float* Wq = (const float*)d_in[1];
  const float* bq = (const float*)d_in[2];
  const float* Wk = (const float*)d_in[3];
  const float* Wv = (const float*)d_in[4];
  const float* bv = (const float*)d_in[5];
  const float* Wo = (const float*)d_in[6];
  const float* bo = (const float*)d_in[7];

  // ws layout (72 MB): xb 32M | wq|wk|wv (6M contiguous = fused 3072x1024) | wo 2M | Qb 32M.
  // K/V bf16 live in d_out (64 MB), consumed by attn before the final GEMM overwrites it.
  if (ws_size < (size_t)75497472) return;
  char* ws = (char*)d_ws;
  s16* xb  = (s16*)(ws);
  s16* wqb = (s16*)(ws + 33554432);
  s16* wkb = (s16*)(ws + 35651584);
  s16* wvb = (s16*)(ws + 37748736);
  s16* wob = (s16*)(ws + 39845888);
  s16* Qb  = (s16*)(ws + 41943040);
  s16* Kb  = (s16*)((char*)d_out);
  s16* Vb  = (s16*)((char*)d_out + 33554432);

  // 1) convert inputs to bf16
  cvt_x<<<8192, 256, 0, stream>>>(x, xb);
  cvt_w<<<2048, 256, 0, stream>>>(Wq, Wk, Wv, Wo, wqb, wkb, wvb, wob);

  // 2) fused QKV projection: [16384x1024] x [3072x1024]^T -> Qb|Kb|Vb (segmented)
  gemm256<true, 12><<<8 * 8 * 12, 512, 0, stream>>>(xb, wqb, bq, nullptr, bv, Qb, Kb, Vb);

  // 3) blockwise attention; O overwrites Qb (block-disjoint, Q staged to LDS first)
  attn_kernel<<<Bb * NBn * Hh, 256, 0, stream>>>(Qb, Kb, Vb, Qb);

  // 4) out = O Wo^T + bo (f32), overwrites K/V scratch in d_out
  gemm256<false, 4><<<8 * 8 * 4, 512, 0, stream>>>(Qb, wob, bo, bo, bo, (float*)d_out, nullptr, nullptr);
}